// Round 15
// baseline (160.032 us; speedup 1.0000x reference)
//
#include <hip/hip_runtime.h>

typedef unsigned short u16;
typedef __attribute__((ext_vector_type(8))) short short8;
typedef __attribute__((ext_vector_type(4))) float f32x4;
typedef __attribute__((ext_vector_type(4))) unsigned short u16x4;

__device__ __forceinline__ u16 f2bf(float f){
  unsigned u = __float_as_uint(f);
  u += 0x7FFFu + ((u >> 16) & 1u);
  return (u16)(u >> 16);
}
__device__ __forceinline__ float bf2f(u16 h){
  return __uint_as_float(((unsigned)h) << 16);
}
__device__ __forceinline__ void gload16(const void* g, void* l){
  __builtin_amdgcn_global_load_lds((const __attribute__((address_space(1))) void*)g,
                                   (__attribute__((address_space(3))) void*)l, 16, 0, 0);
}
__device__ __forceinline__ f32x4 mfma16(short8 a, short8 b, f32x4 c){
  return __builtin_amdgcn_mfma_f32_16x16x32_bf16(a, b, c, 0, 0, 0);
}
__device__ __forceinline__ short8 ld8(const u16* p){
  return *reinterpret_cast<const short8*>(p);
}
__device__ __forceinline__ unsigned cvtpk(float lo, float hi){
  unsigned r;
  asm volatile("v_cvt_pk_bf16_f32 %0, %1, %2" : "=v"(r) : "v"(lo), "v"(hi));
  return r;
}

// ---------------- 32x32 transpose-convert body (dynamic smem) ----------------
__device__ __forceinline__
void transp_body(const float* __restrict__ S, u16* __restrict__ D,
                 int K, int C, int kb, int cb, char* smem){
  float (*t)[33] = (float (*)[33])smem;
  int tx = threadIdx.x & 31, ty = threadIdx.x >> 5;
  #pragma unroll
  for (int i = ty; i < 32; i += 8)
    t[i][tx] = S[(size_t)(kb + i) * C + cb + tx];
  __syncthreads();
  #pragma unroll
  for (int i = ty; i < 32; i += 8)
    D[(size_t)(cb + i) * K + kb + tx] = f2bf(t[tx][i]);
}

// ---------------- prep: f32->bf16 convert (x0,x1) + qkv weight transposes ----------------
__global__ __launch_bounds__(256)
void prep_all(const float* __restrict__ x0, const float* __restrict__ x1,
              u16* __restrict__ x0b, u16* __restrict__ x1b,
              const float* q0_w, const float* kv0_w, const float* q1_w,
              const float* kv1_w, u16* qkv0T, u16* qkv1T){
  __shared__ __align__(16) char smem[4352];
  int bid = blockIdx.x;
  if (bid < 7168){
    const float* s; u16* d; int i;
    if (bid < 6144){ s = x0; d = x0b; i = bid * 256 + threadIdx.x; }
    else           { s = x1; d = x1b; i = (bid - 6144) * 256 + threadIdx.x; }
    float4 v = reinterpret_cast<const float4*>(s)[i];
    u16x4 o = { f2bf(v.x), f2bf(v.y), f2bf(v.z), f2bf(v.w) };
    reinterpret_cast<u16x4*>(d)[i] = o;
    return;
  }
  bid -= 7168;
  const float* S; u16* D; int K, C, nkc, lid;
  if (bid < 4096){
    S = q0_w; D = qkv0T; K = 2048; C = 256; lid = bid;
  } else if (bid < 5120){
    S = kv0_w; D = qkv0T + (size_t)2048*2048; K = 2048; C = 256; lid = bid - 4096;
  } else if (bid < 7168){
    S = q1_w; D = qkv1T; K = 1024; C = 256; lid = bid - 5120;
  } else {
    S = kv1_w; D = qkv1T + (size_t)2048*1024; K = 1024; C = 256; lid = bid - 7168;
  }
  nkc = (K >> 5) * (C >> 5);
  int z   = lid / nkc;
  int rem = lid - z * nkc;
  int kb  = (rem / (C >> 5)) << 5;
  int cb  = (rem % (C >> 5)) << 5;
  transp_body(S + (size_t)z * K * C, D + (size_t)z * K * C, K, C, kb, cb, smem);
}

// ---------------- bf16 GEMM body, 128x128 tile, BK=64, single-barrier T3 loop ----------------
__device__ __forceinline__
void gemm_body(const u16* __restrict__ A, int lda, int aS, int aT, int aOff,
               const u16* __restrict__ BT, int ldbt,
               u16* __restrict__ Cb, float* __restrict__ Cf, int ldc,
               int cS, int cT, int cOff, int N, int Kd, int bid, char* smem){
  int ntx = N >> 7;
  int bm = bid / ntx;
  int bn = bid - bm * ntx;
  int row0 = bm << 7, col0 = bn << 7;
  size_t arow0 = (size_t)(row0 / aS) * aT + (row0 % aS) + aOff;
  size_t crow0 = (size_t)(row0 / cS) * cT + (row0 % cS) + cOff;
  const u16* Abase = A + arow0 * (size_t)lda;
  const u16* Bbase = BT + (size_t)col0 * ldbt;
  int tid = threadIdx.x;
  int w = tid >> 6, l = tid & 63;
  int wr = (w >> 1) << 6, wc = (w & 1) << 6;
  int lr = l & 15, g4 = l >> 4, lq = (l >> 4) << 2;
  int keyr = lr & 7;
  f32x4 acc[4][4];
  #pragma unroll
  for (int m = 0; m < 4; m++)
    #pragma unroll
    for (int n = 0; n < 4; n++)
      acc[m][n] = (f32x4){0.f, 0.f, 0.f, 0.f};
  int scol = (((tid & 7) ^ ((tid >> 3) & 7)) << 3);
  const u16* gA = Abase + (size_t)(tid >> 3) * lda + scol;
  const u16* gB = Bbase + (size_t)(tid >> 3) * ldbt + scol;
  int dsto = tid * 16;

  auto STAGE = [&](char* dst, int k0){
    gload16(gA + k0,                      dst + dsto);
    gload16(gA + (size_t)32*lda  + k0,    dst + 4096  + dsto);
    gload16(gA + (size_t)64*lda  + k0,    dst + 8192  + dsto);
    gload16(gA + (size_t)96*lda  + k0,    dst + 12288 + dsto);
    gload16(gB + k0,                      dst + 16384 + dsto);
    gload16(gB + (size_t)32*ldbt + k0,    dst + 20480 + dsto);
    gload16(gB + (size_t)64*ldbt + k0,    dst + 24576 + dsto);
    gload16(gB + (size_t)96*ldbt + k0,    dst + 28672 + dsto);
  };

  STAGE(smem, 0);
  int cur = 0;
  for (int k0 = 0; k0 < Kd; k0 += 64, cur ^= 1){
    asm volatile("s_waitcnt vmcnt(0)" ::: "memory");
    __builtin_amdgcn_s_barrier();
    asm volatile("" ::: "memory");
    if (k0 + 64 < Kd)
      STAGE(smem + (cur ^ 1) * 32768, k0 + 64);
    const u16* As = (const u16*)(smem + cur * 32768);
    const u16* Bs = As + 8192;
    #pragma unroll
    for (int kk = 0; kk < 2; kk++){
      int so = ((g4 + kk*4) ^ keyr) << 3;
      short8 af[4], bfr[4];
      #pragma unroll
      for (int m = 0; m < 4; m++)
        af[m] = ld8(&As[(wr + m*16 + lr)*64 + so]);
      #pragma unroll
      for (int n = 0; n < 4; n++)
        bfr[n] = ld8(&Bs[(wc + n*16 + lr)*64 + so]);
      #pragma unroll
      for (int m = 0; m < 4; m++)
        #pragma unroll
        for (int n = 0; n < 4; n++)
          acc[m][n] = mfma16(af[m], bfr[n], acc[m][n]);
    }
  }
  #pragma unroll
  for (int m = 0; m < 4; m++){
    #pragma unroll
    for (int i = 0; i < 4; i++){
      size_t r = crow0 + wr + m*16 + lq + i;
      if (Cb){
        #pragma unroll
        for (int n = 0; n < 4; n++)
          Cb[r*ldc + col0 + wc + n*16 + lr] = f2bf(acc[m][n][i]);
      } else {
        #pragma unroll
        for (int n = 0; n < 4; n++)
          Cf[r*ldc + col0 + wc + n*16 + lr] = acc[m][n][i];
      }
    }
  }
}

// merged qkv projections + out-weight transposes (fill idle HBM BW during gemm):
// blocks [0,480) seg0 gemm; [480,640) seg1 gemm; [640,4736) o0_w transpose;
// [4736,6784) o1_w transpose. o0T/o1T consumed only by gemm_out (launched later).
__global__ __launch_bounds__(256)
void gemm_qkv(const u16* __restrict__ x0b, const u16* __restrict__ qkv0T,
              const u16* __restrict__ x1b, const u16* __restrict__ qkv1T,
              u16* __restrict__ qkvb,
              const float* __restrict__ o0_w, const float* __restrict__ o1_w,
              u16* __restrict__ o0T, u16* __restrict__ o1T){
  extern __shared__ __align__(16) char smem[];
  int bid = blockIdx.x;
  if (bid < 480){
    gemm_body(x0b, 2048, 3072, 3072, 0, qkv0T, 2048,
              qkvb, nullptr, 2560, 768, 1024, 0, 2560, 2048, bid, smem);
    return;
  }
  if (bid < 640){
    gemm_body(x1b, 1024, 1024, 1024, 0, qkv1T, 1024,
              qkvb, nullptr, 2560, 256, 1024, 768, 2560, 1024, bid - 480, smem);
    return;
  }
  int lid = bid - 640;
  const float* S; u16* D; int K, C;
  if (lid < 4096){ S = o0_w; D = o0T; K = 2048; C = 2048; }
  else           { S = o1_w; D = o1T; K = 2048; C = 1024; lid -= 4096; }
  int kb = (lid / (C >> 5)) << 5;
  int cb = (lid % (C >> 5)) << 5;
  transp_body(S, D, K, C, kb, cb, smem);
}

__global__ __launch_bounds__(256)
void gemm_out(const u16* __restrict__ encb, const u16* __restrict__ o0T,
              const u16* __restrict__ o1T, float* __restrict__ out0,
              float* __restrict__ out1){
  extern __shared__ __align__(16) char smem[];
  int bid = blockIdx.x;
  if (bid < 384)
    gemm_body(encb, 2048, 768, 1024, 0, o0T, 2048,
              nullptr, out0, 2048, 3072, 3072, 0, 2048, 2048, bid, smem);
  else
    gemm_body(encb, 2048, 256, 1024, 768, o1T, 2048,
              nullptr, out1, 1024, 1024, 1024, 0, 1024, 2048, bid - 384, smem);
}

// ---------------- merged RoPE + transpose_v ----------------
__global__ __launch_bounds__(256)
void rope_tv(u16* __restrict__ qkv, const int* __restrict__ positions,
             float* __restrict__ k_out, float* __restrict__ v_out,
             float* __restrict__ idx_out, u16* __restrict__ vT){
  int bid = blockIdx.x;
  int tid = threadIdx.x;
  if (bid < 2048){
    int bt = bid*2 + (tid >> 7);
    int j = tid & 127;
    float pos = (float)positions[bt];
    float ts = powf(10000.0f, (float)j * 0.0078125f);
    float rad = pos / ts;
    float sn, cs;
    sincosf(rad, &sn, &cs);
    u16* q = qkv + (size_t)bt * 2560;
    #pragma unroll
    for (int n = 0; n < 8; n++){
      float x1 = bf2f(q[n*256 + j]);
      float x2 = bf2f(q[n*256 + 128 + j]);
      q[n*256 + j]       = f2bf((x1*cs - x2*sn) * 0.0625f);
      q[n*256 + 128 + j] = f2bf((x2*cs + x1*sn) * 0.0625f);
    }
    u16* kv = q + 2048;
    float x1 = bf2f(kv[j]), x2 = bf2f(kv[128 + j]);
    float k1 = x1*cs - x2*sn, k2 = x2*cs + x1*sn;
    kv[j] = f2bf(k1); kv[128 + j] = f2bf(k2);
    size_t ko = (size_t)bt * 256;
    k_out[ko + j] = k1;  k_out[ko + 128 + j] = k2;
    v_out[ko + j] = bf2f(kv[256 + j]);
    v_out[ko + 128 + j] = bf2f(kv[384 + j]);
    if (bt == 0 && j < 4 && tid < 128) idx_out[j] = 1024.0f;
    return;
  }
  __shared__ u16 t[32][33];
  int lid = bid - 2048;
  int b = lid >> 8;
  int rem = lid & 255;
  int tb = (rem >> 3) << 5;
  int hb = (rem & 7) << 5;
  int tx = tid & 31, ty = tid >> 5;
  #pragma unroll
  for (int i = ty; i < 32; i += 8)
    t[i][tx] = qkv[(size_t)(b*1024 + tb + i)*2560 + 2304 + hb + tx];
  __syncthreads();
  #pragma unroll
  for (int i = ty; i < 32; i += 8)
    vT[(size_t)(b*256 + hb + i)*1024 + tb + tx] = t[tx][i];
}

// ---------------- flash attention v9: anti-correlated block pairing ----
__global__ __launch_bounds__(256, 2)
void attn_kernel(const u16* __restrict__ qkv, const u16* __restrict__ vT,
                 u16* __restrict__ enc){
  extern __shared__ __align__(16) char smem[];
  int bid = blockIdx.x;
  int b   = bid & 3;
  int h2  = (bid >> 2) & 1;
  int idx = (bid >> 3) & 31;
  int qt  = (bid < 256) ? (63 - idx) : idx;
  int tid = threadIdx.x;
  int w = tid >> 6;
  int head = h2*4 + w;
  int l = tid & 63;
  int lr = l & 15;
  int g = l >> 4;
  int lkqe  = g << 3;
  int lkq16 = g << 4;
  int q0 = qt << 4, nkv = q0 + 16;
  int swk = (lr & 7) << 4;
  int swv = ((lr >> 1) & 3) << 4;

  const char* kbase = (const char*)qkv + (size_t)b*5242880 + 4096;
  const char* vbase = (const char*)vT + (size_t)b*524288;
  const char* ksrc[4]; const char* vsrc[4];
  int kldo[4], vldo[4];
  #pragma unroll
  for (int r = 0; r < 4; r++){
    int o = r*4096 + tid*16;
    int krow = o >> 9;
    int kcol = (o & 511) ^ ((krow & 7) << 4);
    ksrc[r] = kbase + (size_t)krow*5120 + kcol;
    kldo[r] = o;
    int vrow = o >> 6;
    int vcol = (o & 63) ^ (((vrow >> 1) & 3) << 4);
    vsrc[r] = vbase + (size_t)vrow*2048 + vcol;
    vldo[r] = 16384 + o;
  }

  const u16* qb = qkv + ((size_t)(b*1024 + q0)) * 2560 + head*256;
  short8 qf[8];
  #pragma unroll
  for (int hf = 0; hf < 8; hf++)
    qf[hf] = ld8(qb + (size_t)lr*2560 + hf*32 + lkqe);

  f32x4 o_[16];
  #pragma unroll
  for (int hf = 0; hf < 16; hf++)
    o_[hf] = (f32x4){0.f,0.f,0.f,0.f};
  float mrow = -3.0e38f, lrow = 0.f;

  auto STAGE = [&](int buf, int kt){
    char* dst = smem + buf*32768;
    #pragma unroll
    for (int r = 0; r < 4; r++)
      gload16(ksrc[r] + (size_t)kt*5120, dst + kldo[r]);
    #pragma unroll
    for (int r = 0; r < 4; r++)
      gload16(vsrc[r] + (size_t)kt*2, dst + vldo[r]);
  };

  STAGE(0, 0);
  int cur = 0;
  for (int kt = 0; kt < nkv; kt += 32, cur ^= 1){
    asm volatile("s_waitcnt vmcnt(0)" ::: "memory");
    __builtin_amdgcn_s_barrier();
    asm volatile("" ::: "memory");
    if (kt + 32 < nkv)
      STAGE(cur ^ 1, kt + 32);

    const char* Kb = smem + cur*32768;
    const char* Vb = Kb + 16384;
    // ---- swapped QK^T: S^T[kv][q] = K * Q ----
    f32x4 s[2];
    s[0] = (f32x4){0.f,0.f,0.f,0.f};
    s[1] = (f32x4){0.f,0.f,0.f,0.f};
    __builtin_amdgcn_s_setprio(1);
    #pragma unroll
    for (int hf = 0; hf < 8; hf++){
      int colb = (hf*64 + lkq16) ^ swk;
      short8 k0 = *(const short8*)(Kb + (size_t)(lr     )*512 + colb);
      short8 k1 = *(const short8*)(Kb + (size_t)(lr + 16)*512 + colb);
      s[0] = mfma16(k0, qf[hf], s[0]);
      s[1] = mfma16(k1, qf[hf], s[1]);
    }
    __builtin_amdgcn_s_setprio(0);
    // ---- causal mask ----
    if (kt + 32 > q0){
      #pragma unroll
      for (int cf = 0; cf < 2; cf++)
        #pragma unroll
        for (int i = 0; i < 4; i++){
          int kv_g = kt + cf*16 + g*4 + i;
          if (kv_g > q0 + lr) s[cf][i] = -1.0e30f;
        }
    }
    // ---- lazy online softmax ----
    float lm = fmaxf(fmaxf(fmaxf(s[0][0], s[0][1]), fmaxf(s[0][2], s[0][3])),
                     fmaxf(fmaxf(s[1][0], s[1][1]), fmaxf(s[1][2], s[1][3])));
    if (__ballot(lm > mrow + 8.f)){
      float m8 = fmaxf(lm, __shfl_xor(lm, 16, 64));
      m8 = fmaxf(m8, __shfl_xor(m8, 32, 64));
      float mn = fmaxf(mrow, m8);
      float corr = __expf(mrow - mn);
      mrow = mn;
      lrow *= corr;
      #pragma unroll
      for (int hf = 0; hf < 16; hf++)
        #pragma unroll
        for (int i = 0; i < 4; i++)
          o_[hf][i] *= corr;
    }
    float p[2][4];
    #pragma unroll
    for (int cf = 0; cf < 2; cf++)
      #pragma unroll
      for (int i = 0; i < 4; i++)
        p[cf][i] = __expf(s[cf][i] - mrow);
    lrow += p[0][0] + p[0][1] + p[0][2] + p[0][3]
          + p[1][0] + p[1][1] + p[1][2] + p[1][3];
    // ---- build PV B-frag in-register ----
    unsigned A0 = cvtpk(p[0][0], p[0][1]);
    unsigned A1 = cvtpk(p[0][2], p[0][3]);
    unsigned B0 = cvtpk(p[1][0], p[1][1]);
    unsigned B1 = cvtpk(p[1][2], p[1][3]);
    unsigned sp0 = (unsigned)__shfl_xor((int)(g < 2 ? A0 : B0), 16, 64);
    unsigned sp1 = (unsigned)__shfl_xor((int)(g < 2 ? A1 : B1), 16, 64);
    unsigned c0  = (unsigned)__shfl_xor((int)(l < 32 ? B0 : A0), 32, 64);
    unsigned c1  = (unsigned)__shfl_xor((int)(l < 32 ? B1 : A1), 32, 64);
    unsigned pc0 = (unsigned)__shfl_xor((int)c0, 16, 64);
    unsigned pc1 = (unsigned)__shfl_xor((int)c1, 16, 64);
    union { unsigned u[4]; short8 v; } pf;
    pf.u[0] = (g == 0) ? A0 : (g == 1) ? pc0 : (g == 2) ? c0  : sp0;
    pf.u[1] = (g == 0) ? A1 : (g == 1) ? pc1 : (g == 2) ? c1  : sp1;
    pf.u[2] = (g == 0) ? sp0 : (g == 1) ? c0 : (g == 2) ? pc0 : B0;
    pf.u[3] = (g == 0) ? sp1 : (g == 1) ? c1 : (g == 2) ? pc1 : B1;
    // ---- PV ----
    __builtin_amdgcn_s_setprio(1);
    #pragma unroll
    for (int hf = 0; hf < 16; hf++){
      const char* vr = Vb + (size_t)(hf*16 + lr)*64;
      short8 v0 = *(const short8*)(vr + (lkq16 ^ swv));
      o_[hf] = mfma16(v0, pf.v, o_[hf]);
    }
    __builtin_amdgcn_s_setprio(0);
  }
  // ---- epilogue ----
  lrow += __shfl_xor(lrow, 16, 64);
  lrow += __shfl_xor(lrow, 32, 64);
  u16* eb = enc + ((size_t)(b*1024 + q0 + lr)) * 2048 + head*256;
  float inv = 1.0f / lrow;
  #pragma unroll
  for (int hf = 0; hf < 16; hf++){
    u16x4 st = { f2bf(o_[hf][0] * inv), f2bf(o_[hf][1] * inv),
                 f2bf(o_[hf][2] * inv), f2bf(o_[hf][3] * inv) };
    *reinterpret_cast<u16x4*>(eb + hf*16 + g*4) = st;
  }
}

extern "C" void kernel_launch(void* const* d_in, const int* in_sizes, int n_in,
                              void* d_out, int out_size, void* d_ws, size_t ws_size,
                              hipStream_t stream){
  const float* x0     = (const float*)d_in[0];
  const float* x1     = (const float*)d_in[1];
  const int*   pos    = (const int*)d_in[2];
  const float* q0_w   = (const float*)d_in[4];
  const float* kv0_w  = (const float*)d_in[5];
  const float* out0_w = (const float*)d_in[6];
  const float* q1_w   = (const float*)d_in[7];
  const float* kv1_w  = (const float*)d_in[8];
  const float* out1_w = (const float*)d_in[9];

  float* out  = (float*)d_out;
  float* out0 = out;
  float* out1 = out + 6291456;
  float* idxp = out + 7340032;
  float* kout = out + 7340036;
  float* vout = out + 8388612;

  char* ws = (char*)d_ws;
  size_t off = 0;
  auto alloc = [&](size_t bytes){
    void* p = ws + off;
    off = (off + bytes + 255) & ~(size_t)255;
    return p;
  };
  u16* x0b   = (u16*)alloc((size_t)6291456 * 2);
  u16* x1b   = (u16*)alloc((size_t)1048576 * 2);
  u16* qkv0T = (u16*)alloc((size_t)2560 * 2048 * 2);
  u16* qkv1T = (u16*)alloc((size_t)2560 * 1024 * 2);
  u16* o0T   = (u16*)alloc((size_t)2048 * 2048 * 2);
  u16* o1T   = (u16*)alloc((size_t)1024 * 2048 * 2);
  u16* qkvb  = (u16*)alloc((size_t)4096 * 2560 * 2);
  u16* vTb   = (u16*)alloc((size_t)4 * 256 * 1024 * 2);
  u16* encb  = (u16*)alloc((size_t)4096 * 2048 * 2);

  hipFuncSetAttribute((const void*)attn_kernel,
                      hipFuncAttributeMaxDynamicSharedMemorySize, 65536);
  hipFuncSetAttribute((const void*)gemm_qkv,
                      hipFuncAttributeMaxDynamicSharedMemorySize, 65536);
  hipFuncSetAttribute((const void*)gemm_out,
                      hipFuncAttributeMaxDynamicSharedMemorySize, 65536);

  prep_all<<<14848, 256, 0, stream>>>(x0, x1, x0b, x1b,
                                      q0_w, kv0_w, q1_w, kv1_w, qkv0T, qkv1T);

  gemm_qkv<<<6784, 256, 65536, stream>>>(x0b, qkv0T, x1b, qkv1T, qkvb,
                                         out0_w, out1_w, o0T, o1T);

  rope_tv<<<3072, 256, 0, stream>>>(qkvb, pos, kout, vout, idxp, vTb);

  attn_kernel<<<512, 256, 65536, stream>>>(qkvb, vTb, encb);

  gemm_out<<<448, 256, 65536, stream>>>(encb, o0T, o1T, out0, out1);
}

// Round 16
// 159.486 us; speedup vs baseline: 1.0034x; 1.0034x over previous
//
#include <hip/hip_runtime.h>

typedef unsigned short u16;
typedef __attribute__((ext_vector_type(8))) short short8;
typedef __attribute__((ext_vector_type(4))) float f32x4;
typedef __attribute__((ext_vector_type(4))) unsigned short u16x4;

__device__ __forceinline__ u16 f2bf(float f){
  unsigned u = __float_as_uint(f);
  u += 0x7FFFu + ((u >> 16) & 1u);
  return (u16)(u >> 16);
}
__device__ __forceinline__ float bf2f(u16 h){
  return __uint_as_float(((unsigned)h) << 16);
}
__device__ __forceinline__ void gload16(const void* g, void* l){
  __builtin_amdgcn_global_load_lds((const __attribute__((address_space(1))) void*)g,
                                   (__attribute__((address_space(3))) void*)l, 16, 0, 0);
}
__device__ __forceinline__ f32x4 mfma16(short8 a, short8 b, f32x4 c){
  return __builtin_amdgcn_mfma_f32_16x16x32_bf16(a, b, c, 0, 0, 0);
}
__device__ __forceinline__ short8 ld8(const u16* p){
  return *reinterpret_cast<const short8*>(p);
}
__device__ __forceinline__ unsigned cvtpk(float lo, float hi){
  unsigned r;
  asm volatile("v_cvt_pk_bf16_f32 %0, %1, %2" : "=v"(r) : "v"(lo), "v"(hi));
  return r;
}

// ---------------- merged prep: f32->bf16 convert (x0,x1) + 6 weight transposes ----------------
__device__ __forceinline__
void transp_body(const float* __restrict__ S, u16* __restrict__ D,
                 int K, int C, int kb, int cb){
  __shared__ float t[32][33];
  int tx = threadIdx.x & 31, ty = threadIdx.x >> 5;
  #pragma unroll
  for (int i = ty; i < 32; i += 8)
    t[i][tx] = S[(size_t)(kb + i) * C + cb + tx];
  __syncthreads();
  #pragma unroll
  for (int i = ty; i < 32; i += 8)
    D[(size_t)(cb + i) * K + kb + tx] = f2bf(t[tx][i]);
}
__global__ __launch_bounds__(256)
void prep_all(const float* __restrict__ x0, const float* __restrict__ x1,
              u16* __restrict__ x0b, u16* __restrict__ x1b,
              const float* q0_w, const float* kv0_w, const float* q1_w,
              const float* kv1_w, const float* o0_w, const float* o1_w,
              u16* qkv0T, u16* qkv1T, u16* o0T, u16* o1T){
  int bid = blockIdx.x;
  if (bid < 7168){
    const float* s; u16* d; int i;
    if (bid < 6144){ s = x0; d = x0b; i = bid * 256 + threadIdx.x; }
    else           { s = x1; d = x1b; i = (bid - 6144) * 256 + threadIdx.x; }
    float4 v = reinterpret_cast<const float4*>(s)[i];
    u16x4 o = { f2bf(v.x), f2bf(v.y), f2bf(v.z), f2bf(v.w) };
    reinterpret_cast<u16x4*>(d)[i] = o;
    return;
  }
  bid -= 7168;
  const float* S; u16* D; int K, C, nkc, lid;
  if (bid < 4096){
    S = q0_w; D = qkv0T; K = 2048; C = 256; lid = bid;
  } else if (bid < 5120){
    S = kv0_w; D = qkv0T + (size_t)2048*2048; K = 2048; C = 256; lid = bid - 4096;
  } else if (bid < 7168){
    S = q1_w; D = qkv1T; K = 1024; C = 256; lid = bid - 5120;
  } else if (bid < 7680){
    S = kv1_w; D = qkv1T + (size_t)2048*1024; K = 1024; C = 256; lid = bid - 7168;
  } else if (bid < 11776){
    S = o0_w; D = o0T; K = 2048; C = 2048; lid = bid - 7680;
  } else {
    S = o1_w; D = o1T; K = 2048; C = 1024; lid = bid - 11776;
  }
  nkc = (K >> 5) * (C >> 5);
  int z   = lid / nkc;
  int rem = lid - z * nkc;
  int kb  = (rem / (C >> 5)) << 5;
  int cb  = (rem % (C >> 5)) << 5;
  transp_body(S + (size_t)z * K * C, D + (size_t)z * K * C, K, C, kb, cb);
}

// ---------------- bf16 GEMM body, 128x128 tile, BK=64, single-barrier T3 loop ----------------
__device__ __forceinline__
void gemm_body(const u16* __restrict__ A, int lda, int aS, int aT, int aOff,
               const u16* __restrict__ BT, int ldbt,
               u16* __restrict__ Cb, float* __restrict__ Cf, int ldc,
               int cS, int cT, int cOff, int N, int Kd, int bid, char* smem){
  int ntx = N >> 7;
  int bm = bid / ntx;
  int bn = bid - bm * ntx;
  int row0 = bm << 7, col0 = bn << 7;
  size_t arow0 = (size_t)(row0 / aS) * aT + (row0 % aS) + aOff;
  size_t crow0 = (size_t)(row0 / cS) * cT + (row0 % cS) + cOff;
  const u16* Abase = A + arow0 * (size_t)lda;
  const u16* Bbase = BT + (size_t)col0 * ldbt;
  int tid = threadIdx.x;
  int w = tid >> 6, l = tid & 63;
  int wr = (w >> 1) << 6, wc = (w & 1) << 6;
  int lr = l & 15, g4 = l >> 4, lq = (l >> 4) << 2;
  int keyr = lr & 7;
  f32x4 acc[4][4];
  #pragma unroll
  for (int m = 0; m < 4; m++)
    #pragma unroll
    for (int n = 0; n < 4; n++)
      acc[m][n] = (f32x4){0.f, 0.f, 0.f, 0.f};
  int scol = (((tid & 7) ^ ((tid >> 3) & 7)) << 3);
  const u16* gA = Abase + (size_t)(tid >> 3) * lda + scol;
  const u16* gB = Bbase + (size_t)(tid >> 3) * ldbt + scol;
  int dsto = tid * 16;

  auto STAGE = [&](char* dst, int k0){
    gload16(gA + k0,                      dst + dsto);
    gload16(gA + (size_t)32*lda  + k0,    dst + 4096  + dsto);
    gload16(gA + (size_t)64*lda  + k0,    dst + 8192  + dsto);
    gload16(gA + (size_t)96*lda  + k0,    dst + 12288 + dsto);
    gload16(gB + k0,                      dst + 16384 + dsto);
    gload16(gB + (size_t)32*ldbt + k0,    dst + 20480 + dsto);
    gload16(gB + (size_t)64*ldbt + k0,    dst + 24576 + dsto);
    gload16(gB + (size_t)96*ldbt + k0,    dst + 28672 + dsto);
  };

  STAGE(smem, 0);
  int cur = 0;
  for (int k0 = 0; k0 < Kd; k0 += 64, cur ^= 1){
    asm volatile("s_waitcnt vmcnt(0)" ::: "memory");
    __builtin_amdgcn_s_barrier();
    asm volatile("" ::: "memory");
    if (k0 + 64 < Kd)
      STAGE(smem + (cur ^ 1) * 32768, k0 + 64);
    const u16* As = (const u16*)(smem + cur * 32768);
    const u16* Bs = As + 8192;
    #pragma unroll
    for (int kk = 0; kk < 2; kk++){
      int so = ((g4 + kk*4) ^ keyr) << 3;
      short8 af[4], bfr[4];
      #pragma unroll
      for (int m = 0; m < 4; m++)
        af[m] = ld8(&As[(wr + m*16 + lr)*64 + so]);
      #pragma unroll
      for (int n = 0; n < 4; n++)
        bfr[n] = ld8(&Bs[(wc + n*16 + lr)*64 + so]);
      #pragma unroll
      for (int m = 0; m < 4; m++)
        #pragma unroll
        for (int n = 0; n < 4; n++)
          acc[m][n] = mfma16(af[m], bfr[n], acc[m][n]);
    }
  }
  #pragma unroll
  for (int m = 0; m < 4; m++){
    #pragma unroll
    for (int i = 0; i < 4; i++){
      size_t r = crow0 + wr + m*16 + lq + i;
      if (Cb){
        #pragma unroll
        for (int n = 0; n < 4; n++)
          Cb[r*ldc + col0 + wc + n*16 + lr] = f2bf(acc[m][n][i]);
      } else {
        #pragma unroll
        for (int n = 0; n < 4; n++)
          Cf[r*ldc + col0 + wc + n*16 + lr] = acc[m][n][i];
      }
    }
  }
}

__global__ __launch_bounds__(256)
void gemm_qkv(const u16* __restrict__ x0b, const u16* __restrict__ qkv0T,
              const u16* __restrict__ x1b, const u16* __restrict__ qkv1T,
              u16* __restrict__ qkvb){
  extern __shared__ __align__(16) char smem[];
  int bid = blockIdx.x;
  if (bid < 480)
    gemm_body(x0b, 2048, 3072, 3072, 0, qkv0T, 2048,
              qkvb, nullptr, 2560, 768, 1024, 0, 2560, 2048, bid, smem);
  else
    gemm_body(x1b, 1024, 1024, 1024, 0, qkv1T, 1024,
              qkvb, nullptr, 2560, 256, 1024, 768, 2560, 1024, bid - 480, smem);
}

__global__ __launch_bounds__(256)
void gemm_out(const u16* __restrict__ encb, const u16* __restrict__ o0T,
              const u16* __restrict__ o1T, float* __restrict__ out0,
              float* __restrict__ out1){
  extern __shared__ __align__(16) char smem[];
  int bid = blockIdx.x;
  if (bid < 384)
    gemm_body(encb, 2048, 768, 1024, 0, o0T, 2048,
              nullptr, out0, 2048, 3072, 3072, 0, 2048, 2048, bid, smem);
  else
    gemm_body(encb, 2048, 256, 1024, 768, o1T, 2048,
              nullptr, out1, 1024, 1024, 1024, 0, 1024, 2048, bid - 384, smem);
}

// ---------------- merged RoPE + transpose_v ----------------
__global__ __launch_bounds__(256)
void rope_tv(u16* __restrict__ qkv, const int* __restrict__ positions,
             float* __restrict__ k_out, float* __restrict__ v_out,
             float* __restrict__ idx_out, u16* __restrict__ vT){
  int bid = blockIdx.x;
  int tid = threadIdx.x;
  if (bid < 2048){
    int bt = bid*2 + (tid >> 7);
    int j = tid & 127;
    float pos = (float)positions[bt];
    float ts = powf(10000.0f, (float)j * 0.0078125f);
    float rad = pos / ts;
    float sn, cs;
    sincosf(rad, &sn, &cs);
    u16* q = qkv + (size_t)bt * 2560;
    #pragma unroll
    for (int n = 0; n < 8; n++){
      float x1 = bf2f(q[n*256 + j]);
      float x2 = bf2f(q[n*256 + 128 + j]);
      q[n*256 + j]       = f2bf((x1*cs - x2*sn) * 0.0625f);
      q[n*256 + 128 + j] = f2bf((x2*cs + x1*sn) * 0.0625f);
    }
    u16* kv = q + 2048;
    float x1 = bf2f(kv[j]), x2 = bf2f(kv[128 + j]);
    float k1 = x1*cs - x2*sn, k2 = x2*cs + x1*sn;
    kv[j] = f2bf(k1); kv[128 + j] = f2bf(k2);
    size_t ko = (size_t)bt * 256;
    k_out[ko + j] = k1;  k_out[ko + 128 + j] = k2;
    v_out[ko + j] = bf2f(kv[256 + j]);
    v_out[ko + 128 + j] = bf2f(kv[384 + j]);
    if (bt == 0 && j < 4 && tid < 128) idx_out[j] = 1024.0f;
    return;
  }
  __shared__ u16 t[32][33];
  int lid = bid - 2048;
  int b = lid >> 8;
  int rem = lid & 255;
  int tb = (rem >> 3) << 5;
  int hb = (rem & 7) << 5;
  int tx = tid & 31, ty = tid >> 5;
  #pragma unroll
  for (int i = ty; i < 32; i += 8)
    t[i][tx] = qkv[(size_t)(b*1024 + tb + i)*2560 + 2304 + hb + tx];
  __syncthreads();
  #pragma unroll
  for (int i = ty; i < 32; i += 8)
    vT[(size_t)(b*256 + hb + i)*1024 + tb + tx] = t[tx][i];
}

// ---------------- flash attention v10: 8-wave blocks (all 8 heads share K/V staging) ----
// Block = 8 waves (8 heads) x 16 q-rows of one (b, qt); KVBLK=32 double-buffered
// (64KB LDS); grid 256 = 1 block/CU. Staging bytes per CU per iter HALVED vs v9
// (h2 pair shared one K/V stream). Single barrier, lazy softmax, in-register P.
__global__ __launch_bounds__(512, 2)
void attn_kernel(const u16* __restrict__ qkv, const u16* __restrict__ vT,
                 u16* __restrict__ enc){
  extern __shared__ __align__(16) char smem[];
  int bid = blockIdx.x;
  int b   = bid & 3;
  int qt  = 63 - (bid >> 2);     // longest-first
  int tid = threadIdx.x;
  int w = tid >> 6;              // head 0..7
  int l = tid & 63;
  int lr = l & 15;
  int g = l >> 4;
  int lkqe  = g << 3;
  int lkq16 = g << 4;
  int q0 = qt << 4, nkv = q0 + 16;
  int swk = (lr & 7) << 4;
  int swv = ((lr >> 1) & 3) << 4;

  const char* kbase = (const char*)qkv + (size_t)b*5242880 + 4096;
  const char* vbase = (const char*)vT + (size_t)b*524288;
  const char* ksrc[2]; const char* vsrc[2];
  int kldo[2], vldo[2];
  #pragma unroll
  for (int r = 0; r < 2; r++){
    int o = r*8192 + tid*16;     // 512 threads x 16B x 2 = 16KB (K); same for V
    int krow = o >> 9;                       // 0..31 (512B rows)
    int kcol = (o & 511) ^ ((krow & 7) << 4);
    ksrc[r] = kbase + (size_t)krow*5120 + kcol;
    kldo[r] = o;
    int vrow = o >> 6;                       // 0..255 (64B rows)
    int vcol = (o & 63) ^ (((vrow >> 1) & 3) << 4);
    vsrc[r] = vbase + (size_t)vrow*2048 + vcol;
    vldo[r] = 16384 + o;
  }

  const u16* qb = qkv + ((size_t)(b*1024 + q0)) * 2560 + w*256;
  short8 qf[8];
  #pragma unroll
  for (int hf = 0; hf < 8; hf++)
    qf[hf] = ld8(qb + (size_t)lr*2560 + hf*32 + lkqe);

  f32x4 o_[16];
  #pragma unroll
  for (int hf = 0; hf < 16; hf++)
    o_[hf] = (f32x4){0.f,0.f,0.f,0.f};
  float mrow = -3.0e38f, lrow = 0.f;

  auto STAGE = [&](int buf, int kt){
    char* dst = smem + buf*32768;
    #pragma unroll
    for (int r = 0; r < 2; r++)
      gload16(ksrc[r] + (size_t)kt*5120, dst + kldo[r]);
    #pragma unroll
    for (int r = 0; r < 2; r++)
      gload16(vsrc[r] + (size_t)kt*2, dst + vldo[r]);
  };

  STAGE(0, 0);
  int cur = 0;
  for (int kt = 0; kt < nkv; kt += 32, cur ^= 1){
    asm volatile("s_waitcnt vmcnt(0)" ::: "memory");
    __builtin_amdgcn_s_barrier();
    asm volatile("" ::: "memory");
    if (kt + 32 < nkv)
      STAGE(cur ^ 1, kt + 32);

    const char* Kb = smem + cur*32768;
    const char* Vb = Kb + 16384;
    // ---- swapped QK^T: S^T[kv][q] = K * Q ----
    f32x4 s[2];
    s[0] = (f32x4){0.f,0.f,0.f,0.f};
    s[1] = (f32x4){0.f,0.f,0.f,0.f};
    __builtin_amdgcn_s_setprio(1);
    #pragma unroll
    for (int hf = 0; hf < 8; hf++){
      int colb = (hf*64 + lkq16) ^ swk;
      short8 k0 = *(const short8*)(Kb + (size_t)(lr     )*512 + colb);
      short8 k1 = *(const short8*)(Kb + (size_t)(lr + 16)*512 + colb);
      s[0] = mfma16(k0, qf[hf], s[0]);
      s[1] = mfma16(k1, qf[hf], s[1]);
    }
    __builtin_amdgcn_s_setprio(0);
    // ---- causal mask: kv = kt + cf*16 + g*4 + i; q = q0 + lr ----
    if (kt + 32 > q0){
      #pragma unroll
      for (int cf = 0; cf < 2; cf++)
        #pragma unroll
        for (int i = 0; i < 4; i++){
          int kv_g = kt + cf*16 + g*4 + i;
          if (kv_g > q0 + lr) s[cf][i] = -1.0e30f;
        }
    }
    // ---- lazy online softmax ----
    float lm = fmaxf(fmaxf(fmaxf(s[0][0], s[0][1]), fmaxf(s[0][2], s[0][3])),
                     fmaxf(fmaxf(s[1][0], s[1][1]), fmaxf(s[1][2], s[1][3])));
    if (__ballot(lm > mrow + 8.f)){
      float m8 = fmaxf(lm, __shfl_xor(lm, 16, 64));
      m8 = fmaxf(m8, __shfl_xor(m8, 32, 64));
      float mn = fmaxf(mrow, m8);
      float corr = __expf(mrow - mn);
      mrow = mn;
      lrow *= corr;
      #pragma unroll
      for (int hf = 0; hf < 16; hf++)
        #pragma unroll
        for (int i = 0; i < 4; i++)
          o_[hf][i] *= corr;
    }
    float p[2][4];
    #pragma unroll
    for (int cf = 0; cf < 2; cf++)
      #pragma unroll
      for (int i = 0; i < 4; i++)
        p[cf][i] = __expf(s[cf][i] - mrow);
    lrow += p[0][0] + p[0][1] + p[0][2] + p[0][3]
          + p[1][0] + p[1][1] + p[1][2] + p[1][3];
    // ---- build PV B-frag in-register ----
    unsigned A0 = cvtpk(p[0][0], p[0][1]);
    unsigned A1 = cvtpk(p[0][2], p[0][3]);
    unsigned B0 = cvtpk(p[1][0], p[1][1]);
    unsigned B1 = cvtpk(p[1][2], p[1][3]);
    unsigned sp0 = (unsigned)__shfl_xor((int)(g < 2 ? A0 : B0), 16, 64);
    unsigned sp1 = (unsigned)__shfl_xor((int)(g < 2 ? A1 : B1), 16, 64);
    unsigned c0  = (unsigned)__shfl_xor((int)(l < 32 ? B0 : A0), 32, 64);
    unsigned c1  = (unsigned)__shfl_xor((int)(l < 32 ? B1 : A1), 32, 64);
    unsigned pc0 = (unsigned)__shfl_xor((int)c0, 16, 64);
    unsigned pc1 = (unsigned)__shfl_xor((int)c1, 16, 64);
    union { unsigned u[4]; short8 v; } pf;
    pf.u[0] = (g == 0) ? A0 : (g == 1) ? pc0 : (g == 2) ? c0  : sp0;
    pf.u[1] = (g == 0) ? A1 : (g == 1) ? pc1 : (g == 2) ? c1  : sp1;
    pf.u[2] = (g == 0) ? sp0 : (g == 1) ? c0 : (g == 2) ? pc0 : B0;
    pf.u[3] = (g == 0) ? sp1 : (g == 1) ? c1 : (g == 2) ? pc1 : B1;
    // ---- PV: O^T[h][q] += V^T[h][kv] * P^T[kv][q] ----
    __builtin_amdgcn_s_setprio(1);
    #pragma unroll
    for (int hf = 0; hf < 16; hf++){
      const char* vr = Vb + (size_t)(hf*16 + lr)*64;
      short8 v0 = *(const short8*)(vr + (lkq16 ^ swv));
      o_[hf] = mfma16(v0, pf.v, o_[hf]);
    }
    __builtin_amdgcn_s_setprio(0);
  }
  // ---- epilogue ----
  lrow += __shfl_xor(lrow, 16, 64);
  lrow += __shfl_xor(lrow, 32, 64);
  u16* eb = enc + ((size_t)(b*1024 + q0 + lr)) * 2048 + w*256;
  float inv = 1.0f / lrow;
  #pragma unroll
  for (int hf = 0; hf < 16; hf++){
    u16x4 st = { f2bf(o_[hf][0] * inv), f2bf(o_[hf][1] * inv),
                 f2bf(o_[hf][2] * inv), f2bf(o_[hf][3] * inv) };
    *reinterpret_cast<u16x4*>(eb + hf*16 + g*4) = st;
  }
}

extern "C" void kernel_launch(void* const* d_in, const int* in_sizes, int n_in,
                              void* d_out, int out_size, void* d_ws, size_t ws_size,
                              hipStream_t stream){
  const float* x0     = (const float*)d_in[0];
  const float* x1     = (const float*)d_in[1];
  const int*   pos    = (const int*)d_in[2];
  const float* q0_w   = (const float*)d_in[4];
  const float* kv0_w  = (const float*)d_in[5];
  const float* out0_w = (const float*)d_in[6];
  const float* q1_w   = (const float*)d_in[7];
  const float* kv1_w  = (const float*)d_in[8];
  const float* out1_w = (const float*)d_in[9];

  float* out  = (float*)d_out;
  float* out0 = out;
  float* out1 = out + 6291456;
  float* idxp = out + 7340032;
  float* kout = out + 7340036;
  float* vout = out + 8388612;

  char* ws = (char*)d_ws;
  size_t off = 0;
  auto alloc = [&](size_t bytes){
    void* p = ws + off;
    off = (off + bytes + 255) & ~(size_t)255;
    return p;
  };
  u16* x0b   = (u16*)alloc((size_t)6291456 * 2);
  u16* x1b   = (u16*)alloc((size_t)1048576 * 2);
  u16* qkv0T = (u16*)alloc((size_t)2560 * 2048 * 2);
  u16* qkv1T = (u16*)alloc((size_t)2560 * 1024 * 2);
  u16* o0T   = (u16*)alloc((size_t)2048 * 2048 * 2);
  u16* o1T   = (u16*)alloc((size_t)1024 * 2048 * 2);
  u16* qkvb  = (u16*)alloc((size_t)4096 * 2560 * 2);
  u16* vTb   = (u16*)alloc((size_t)4 * 256 * 1024 * 2);
  u16* encb  = (u16*)alloc((size_t)4096 * 2048 * 2);

  hipFuncSetAttribute((const void*)attn_kernel,
                      hipFuncAttributeMaxDynamicSharedMemorySize, 65536);
  hipFuncSetAttribute((const void*)gemm_qkv,
                      hipFuncAttributeMaxDynamicSharedMemorySize, 65536);
  hipFuncSetAttribute((const void*)gemm_out,
                      hipFuncAttributeMaxDynamicSharedMemorySize, 65536);

  prep_all<<<20992, 256, 0, stream>>>(x0, x1, x0b, x1b,
                                      q0_w, kv0_w, q1_w, kv1_w, out0_w, out1_w,
                                      qkv0T, qkv1T, o0T, o1T);

  gemm_qkv<<<640, 256, 65536, stream>>>(x0b, qkv0T, x1b, qkv1T, qkvb);

  rope_tv<<<3072, 256, 0, stream>>>(qkvb, pos, kout, vout, idxp, vTb);

  attn_kernel<<<256, 512, 65536, stream>>>(qkvb, vTb, encb);

  gemm_out<<<448, 256, 65536, stream>>>(encb, o0T, o1T, out0, out1);
}

// Round 17
// 151.807 us; speedup vs baseline: 1.0542x; 1.0506x over previous
//
#include <hip/hip_runtime.h>

typedef unsigned short u16;
typedef __attribute__((ext_vector_type(8))) short short8;
typedef __attribute__((ext_vector_type(4))) float f32x4;
typedef __attribute__((ext_vector_type(4))) unsigned short u16x4;

__device__ __forceinline__ u16 f2bf(float f){
  unsigned u = __float_as_uint(f);
  u += 0x7FFFu + ((u >> 16) & 1u);
  return (u16)(u >> 16);
}
__device__ __forceinline__ float bf2f(u16 h){
  return __uint_as_float(((unsigned)h) << 16);
}
__device__ __forceinline__ void gload16(const void* g, void* l){
  __builtin_amdgcn_global_load_lds((const __attribute__((address_space(1))) void*)g,
                                   (__attribute__((address_space(3))) void*)l, 16, 0, 0);
}
__device__ __forceinline__ f32x4 mfma16(short8 a, short8 b, f32x4 c){
  return __builtin_amdgcn_mfma_f32_16x16x32_bf16(a, b, c, 0, 0, 0);
}
__device__ __forceinline__ short8 ld8(const u16* p){
  return *reinterpret_cast<const short8*>(p);
}
__device__ __forceinline__ unsigned cvtpk(float lo, float hi){
  unsigned r;
  asm volatile("v_cvt_pk_bf16_f32 %0, %1, %2" : "=v"(r) : "v"(lo), "v"(hi));
  return r;
}

// ---------------- merged prep: f32->bf16 convert (x0,x1) + 6 weight transposes ----------------
__device__ __forceinline__
void transp_body(const float* __restrict__ S, u16* __restrict__ D,
                 int K, int C, int kb, int cb){
  __shared__ float t[32][33];
  int tx = threadIdx.x & 31, ty = threadIdx.x >> 5;
  #pragma unroll
  for (int i = ty; i < 32; i += 8)
    t[i][tx] = S[(size_t)(kb + i) * C + cb + tx];
  __syncthreads();
  #pragma unroll
  for (int i = ty; i < 32; i += 8)
    D[(size_t)(cb + i) * K + kb + tx] = f2bf(t[tx][i]);
}
__global__ __launch_bounds__(256)
void prep_all(const float* __restrict__ x0, const float* __restrict__ x1,
              u16* __restrict__ x0b, u16* __restrict__ x1b,
              const float* q0_w, const float* kv0_w, const float* q1_w,
              const float* kv1_w, const float* o0_w, const float* o1_w,
              u16* qkv0T, u16* qkv1T, u16* o0T, u16* o1T){
  int bid = blockIdx.x;
  if (bid < 7168){
    const float* s; u16* d; int i;
    if (bid < 6144){ s = x0; d = x0b; i = bid * 256 + threadIdx.x; }
    else           { s = x1; d = x1b; i = (bid - 6144) * 256 + threadIdx.x; }
    float4 v = reinterpret_cast<const float4*>(s)[i];
    u16x4 o = { f2bf(v.x), f2bf(v.y), f2bf(v.z), f2bf(v.w) };
    reinterpret_cast<u16x4*>(d)[i] = o;
    return;
  }
  bid -= 7168;
  const float* S; u16* D; int K, C, nkc, lid;
  if (bid < 4096){
    S = q0_w; D = qkv0T; K = 2048; C = 256; lid = bid;
  } else if (bid < 5120){
    S = kv0_w; D = qkv0T + (size_t)2048*2048; K = 2048; C = 256; lid = bid - 4096;
  } else if (bid < 7168){
    S = q1_w; D = qkv1T; K = 1024; C = 256; lid = bid - 5120;
  } else if (bid < 7680){
    S = kv1_w; D = qkv1T + (size_t)2048*1024; K = 1024; C = 256; lid = bid - 7168;
  } else if (bid < 11776){
    S = o0_w; D = o0T; K = 2048; C = 2048; lid = bid - 7680;
  } else {
    S = o1_w; D = o1T; K = 2048; C = 1024; lid = bid - 11776;
  }
  nkc = (K >> 5) * (C >> 5);
  int z   = lid / nkc;
  int rem = lid - z * nkc;
  int kb  = (rem / (C >> 5)) << 5;
  int cb  = (rem % (C >> 5)) << 5;
  transp_body(S + (size_t)z * K * C, D + (size_t)z * K * C, K, C, kb, cb);
}

// ---------------- bf16 GEMM body, 128x128 tile, BK=64, single-barrier T3 loop ----------------
__device__ __forceinline__
void gemm_body(const u16* __restrict__ A, int lda, int aS, int aT, int aOff,
               const u16* __restrict__ BT, int ldbt,
               u16* __restrict__ Cb, float* __restrict__ Cf, int ldc,
               int cS, int cT, int cOff, int N, int Kd, int bid, char* smem){
  int ntx = N >> 7;
  int bm = bid / ntx;
  int bn = bid - bm * ntx;
  int row0 = bm << 7, col0 = bn << 7;
  size_t arow0 = (size_t)(row0 / aS) * aT + (row0 % aS) + aOff;
  size_t crow0 = (size_t)(row0 / cS) * cT + (row0 % cS) + cOff;
  const u16* Abase = A + arow0 * (size_t)lda;
  const u16* Bbase = BT + (size_t)col0 * ldbt;
  int tid = threadIdx.x;
  int w = tid >> 6, l = tid & 63;
  int wr = (w >> 1) << 6, wc = (w & 1) << 6;
  int lr = l & 15, g4 = l >> 4, lq = (l >> 4) << 2;
  int keyr = lr & 7;
  f32x4 acc[4][4];
  #pragma unroll
  for (int m = 0; m < 4; m++)
    #pragma unroll
    for (int n = 0; n < 4; n++)
      acc[m][n] = (f32x4){0.f, 0.f, 0.f, 0.f};
  int scol = (((tid & 7) ^ ((tid >> 3) & 7)) << 3);
  const u16* gA = Abase + (size_t)(tid >> 3) * lda + scol;
  const u16* gB = Bbase + (size_t)(tid >> 3) * ldbt + scol;
  int dsto = tid * 16;

  auto STAGE = [&](char* dst, int k0){
    gload16(gA + k0,                      dst + dsto);
    gload16(gA + (size_t)32*lda  + k0,    dst + 4096  + dsto);
    gload16(gA + (size_t)64*lda  + k0,    dst + 8192  + dsto);
    gload16(gA + (size_t)96*lda  + k0,    dst + 12288 + dsto);
    gload16(gB + k0,                      dst + 16384 + dsto);
    gload16(gB + (size_t)32*ldbt + k0,    dst + 20480 + dsto);
    gload16(gB + (size_t)64*ldbt + k0,    dst + 24576 + dsto);
    gload16(gB + (size_t)96*ldbt + k0,    dst + 28672 + dsto);
  };

  STAGE(smem, 0);
  int cur = 0;
  for (int k0 = 0; k0 < Kd; k0 += 64, cur ^= 1){
    asm volatile("s_waitcnt vmcnt(0)" ::: "memory");
    __builtin_amdgcn_s_barrier();
    asm volatile("" ::: "memory");
    if (k0 + 64 < Kd)
      STAGE(smem + (cur ^ 1) * 32768, k0 + 64);
    const u16* As = (const u16*)(smem + cur * 32768);
    const u16* Bs = As + 8192;
    #pragma unroll
    for (int kk = 0; kk < 2; kk++){
      int so = ((g4 + kk*4) ^ keyr) << 3;
      short8 af[4], bfr[4];
      #pragma unroll
      for (int m = 0; m < 4; m++)
        af[m] = ld8(&As[(wr + m*16 + lr)*64 + so]);
      #pragma unroll
      for (int n = 0; n < 4; n++)
        bfr[n] = ld8(&Bs[(wc + n*16 + lr)*64 + so]);
      #pragma unroll
      for (int m = 0; m < 4; m++)
        #pragma unroll
        for (int n = 0; n < 4; n++)
          acc[m][n] = mfma16(af[m], bfr[n], acc[m][n]);
    }
  }
  #pragma unroll
  for (int m = 0; m < 4; m++){
    #pragma unroll
    for (int i = 0; i < 4; i++){
      size_t r = crow0 + wr + m*16 + lq + i;
      if (Cb){
        #pragma unroll
        for (int n = 0; n < 4; n++)
          Cb[r*ldc + col0 + wc + n*16 + lr] = f2bf(acc[m][n][i]);
      } else {
        #pragma unroll
        for (int n = 0; n < 4; n++)
          Cf[r*ldc + col0 + wc + n*16 + lr] = acc[m][n][i];
      }
    }
  }
}

__global__ __launch_bounds__(256)
void gemm_qkv(const u16* __restrict__ x0b, const u16* __restrict__ qkv0T,
              const u16* __restrict__ x1b, const u16* __restrict__ qkv1T,
              u16* __restrict__ qkvb){
  extern __shared__ __align__(16) char smem[];
  int bid = blockIdx.x;
  if (bid < 480)
    gemm_body(x0b, 2048, 3072, 3072, 0, qkv0T, 2048,
              qkvb, nullptr, 2560, 768, 1024, 0, 2560, 2048, bid, smem);
  else
    gemm_body(x1b, 1024, 1024, 1024, 0, qkv1T, 1024,
              qkvb, nullptr, 2560, 256, 1024, 768, 2560, 1024, bid - 480, smem);
}

__global__ __launch_bounds__(256)
void gemm_out(const u16* __restrict__ encb, const u16* __restrict__ o0T,
              const u16* __restrict__ o1T, float* __restrict__ out0,
              float* __restrict__ out1){
  extern __shared__ __align__(16) char smem[];
  int bid = blockIdx.x;
  if (bid < 384)
    gemm_body(encb, 2048, 768, 1024, 0, o0T, 2048,
              nullptr, out0, 2048, 3072, 3072, 0, 2048, 2048, bid, smem);
  else
    gemm_body(encb, 2048, 256, 1024, 768, o1T, 2048,
              nullptr, out1, 1024, 1024, 1024, 0, 1024, 2048, bid - 384, smem);
}

// ---------------- merged RoPE + transpose_v ----------------
__global__ __launch_bounds__(256)
void rope_tv(u16* __restrict__ qkv, const int* __restrict__ positions,
             float* __restrict__ k_out, float* __restrict__ v_out,
             float* __restrict__ idx_out, u16* __restrict__ vT){
  int bid = blockIdx.x;
  int tid = threadIdx.x;
  if (bid < 2048){
    int bt = bid*2 + (tid >> 7);
    int j = tid & 127;
    float pos = (float)positions[bt];
    float ts = powf(10000.0f, (float)j * 0.0078125f);
    float rad = pos / ts;
    float sn, cs;
    sincosf(rad, &sn, &cs);
    u16* q = qkv + (size_t)bt * 2560;
    #pragma unroll
    for (int n = 0; n < 8; n++){
      float x1 = bf2f(q[n*256 + j]);
      float x2 = bf2f(q[n*256 + 128 + j]);
      q[n*256 + j]       = f2bf((x1*cs - x2*sn) * 0.0625f);
      q[n*256 + 128 + j] = f2bf((x2*cs + x1*sn) * 0.0625f);
    }
    u16* kv = q + 2048;
    float x1 = bf2f(kv[j]), x2 = bf2f(kv[128 + j]);
    float k1 = x1*cs - x2*sn, k2 = x2*cs + x1*sn;
    kv[j] = f2bf(k1); kv[128 + j] = f2bf(k2);
    size_t ko = (size_t)bt * 256;
    k_out[ko + j] = k1;  k_out[ko + 128 + j] = k2;
    v_out[ko + j] = bf2f(kv[256 + j]);
    v_out[ko + 128 + j] = bf2f(kv[384 + j]);
    if (bt == 0 && j < 4 && tid < 128) idx_out[j] = 1024.0f;
    return;
  }
  __shared__ u16 t[32][33];
  int lid = bid - 2048;
  int b = lid >> 8;
  int rem = lid & 255;
  int tb = (rem >> 3) << 5;
  int hb = (rem & 7) << 5;
  int tx = tid & 31, ty = tid >> 5;
  #pragma unroll
  for (int i = ty; i < 32; i += 8)
    t[i][tx] = qkv[(size_t)(b*1024 + tb + i)*2560 + 2304 + hb + tx];
  __syncthreads();
  #pragma unroll
  for (int i = ty; i < 32; i += 8)
    vT[(size_t)(b*256 + hb + i)*1024 + tb + tx] = t[tx][i];
}

// ---------------- flash attention v9 (R14 best): anti-correlated block pairing ----
// 4-wave blocks (4 heads x 16 q), KVBLK=32, 2 blocks/CU, LDS = 2x32KB dbuf.
// bid<256 -> qt=63-(bid>>3), bid>=256 -> qt=(bid-256)>>3: round-robin pairs sum
// to 65 iterations/CU. Single barrier, lazy softmax, in-register P, setprio.
__global__ __launch_bounds__(256, 2)
void attn_kernel(const u16* __restrict__ qkv, const u16* __restrict__ vT,
                 u16* __restrict__ enc){
  extern __shared__ __align__(16) char smem[];
  int bid = blockIdx.x;
  int b   = bid & 3;
  int h2  = (bid >> 2) & 1;
  int idx = (bid >> 3) & 31;
  int qt  = (bid < 256) ? (63 - idx) : idx;
  int tid = threadIdx.x;
  int w = tid >> 6;
  int head = h2*4 + w;
  int l = tid & 63;
  int lr = l & 15;
  int g = l >> 4;
  int lkqe  = g << 3;
  int lkq16 = g << 4;
  int q0 = qt << 4, nkv = q0 + 16;
  int swk = (lr & 7) << 4;
  int swv = ((lr >> 1) & 3) << 4;

  const char* kbase = (const char*)qkv + (size_t)b*5242880 + 4096;
  const char* vbase = (const char*)vT + (size_t)b*524288;
  const char* ksrc[4]; const char* vsrc[4];
  int kldo[4], vldo[4];
  #pragma unroll
  for (int r = 0; r < 4; r++){
    int o = r*4096 + tid*16;
    int krow = o >> 9;
    int kcol = (o & 511) ^ ((krow & 7) << 4);
    ksrc[r] = kbase + (size_t)krow*5120 + kcol;
    kldo[r] = o;
    int vrow = o >> 6;
    int vcol = (o & 63) ^ (((vrow >> 1) & 3) << 4);
    vsrc[r] = vbase + (size_t)vrow*2048 + vcol;
    vldo[r] = 16384 + o;
  }

  const u16* qb = qkv + ((size_t)(b*1024 + q0)) * 2560 + head*256;
  short8 qf[8];
  #pragma unroll
  for (int hf = 0; hf < 8; hf++)
    qf[hf] = ld8(qb + (size_t)lr*2560 + hf*32 + lkqe);

  f32x4 o_[16];
  #pragma unroll
  for (int hf = 0; hf < 16; hf++)
    o_[hf] = (f32x4){0.f,0.f,0.f,0.f};
  float mrow = -3.0e38f, lrow = 0.f;

  auto STAGE = [&](int buf, int kt){
    char* dst = smem + buf*32768;
    #pragma unroll
    for (int r = 0; r < 4; r++)
      gload16(ksrc[r] + (size_t)kt*5120, dst + kldo[r]);
    #pragma unroll
    for (int r = 0; r < 4; r++)
      gload16(vsrc[r] + (size_t)kt*2, dst + vldo[r]);
  };

  STAGE(0, 0);
  int cur = 0;
  for (int kt = 0; kt < nkv; kt += 32, cur ^= 1){
    asm volatile("s_waitcnt vmcnt(0)" ::: "memory");
    __builtin_amdgcn_s_barrier();
    asm volatile("" ::: "memory");
    if (kt + 32 < nkv)
      STAGE(cur ^ 1, kt + 32);

    const char* Kb = smem + cur*32768;
    const char* Vb = Kb + 16384;
    // ---- swapped QK^T: S^T[kv][q] = K * Q ----
    f32x4 s[2];
    s[0] = (f32x4){0.f,0.f,0.f,0.f};
    s[1] = (f32x4){0.f,0.f,0.f,0.f};
    __builtin_amdgcn_s_setprio(1);
    #pragma unroll
    for (int hf = 0; hf < 8; hf++){
      int colb = (hf*64 + lkq16) ^ swk;
      short8 k0 = *(const short8*)(Kb + (size_t)(lr     )*512 + colb);
      short8 k1 = *(const short8*)(Kb + (size_t)(lr + 16)*512 + colb);
      s[0] = mfma16(k0, qf[hf], s[0]);
      s[1] = mfma16(k1, qf[hf], s[1]);
    }
    __builtin_amdgcn_s_setprio(0);
    // ---- causal mask ----
    if (kt + 32 > q0){
      #pragma unroll
      for (int cf = 0; cf < 2; cf++)
        #pragma unroll
        for (int i = 0; i < 4; i++){
          int kv_g = kt + cf*16 + g*4 + i;
          if (kv_g > q0 + lr) s[cf][i] = -1.0e30f;
        }
    }
    // ---- lazy online softmax ----
    float lm = fmaxf(fmaxf(fmaxf(s[0][0], s[0][1]), fmaxf(s[0][2], s[0][3])),
                     fmaxf(fmaxf(s[1][0], s[1][1]), fmaxf(s[1][2], s[1][3])));
    if (__ballot(lm > mrow + 8.f)){
      float m8 = fmaxf(lm, __shfl_xor(lm, 16, 64));
      m8 = fmaxf(m8, __shfl_xor(m8, 32, 64));
      float mn = fmaxf(mrow, m8);
      float corr = __expf(mrow - mn);
      mrow = mn;
      lrow *= corr;
      #pragma unroll
      for (int hf = 0; hf < 16; hf++)
        #pragma unroll
        for (int i = 0; i < 4; i++)
          o_[hf][i] *= corr;
    }
    float p[2][4];
    #pragma unroll
    for (int cf = 0; cf < 2; cf++)
      #pragma unroll
      for (int i = 0; i < 4; i++)
        p[cf][i] = __expf(s[cf][i] - mrow);
    lrow += p[0][0] + p[0][1] + p[0][2] + p[0][3]
          + p[1][0] + p[1][1] + p[1][2] + p[1][3];
    // ---- build PV B-frag in-register ----
    unsigned A0 = cvtpk(p[0][0], p[0][1]);
    unsigned A1 = cvtpk(p[0][2], p[0][3]);
    unsigned B0 = cvtpk(p[1][0], p[1][1]);
    unsigned B1 = cvtpk(p[1][2], p[1][3]);
    unsigned sp0 = (unsigned)__shfl_xor((int)(g < 2 ? A0 : B0), 16, 64);
    unsigned sp1 = (unsigned)__shfl_xor((int)(g < 2 ? A1 : B1), 16, 64);
    unsigned c0  = (unsigned)__shfl_xor((int)(l < 32 ? B0 : A0), 32, 64);
    unsigned c1  = (unsigned)__shfl_xor((int)(l < 32 ? B1 : A1), 32, 64);
    unsigned pc0 = (unsigned)__shfl_xor((int)c0, 16, 64);
    unsigned pc1 = (unsigned)__shfl_xor((int)c1, 16, 64);
    union { unsigned u[4]; short8 v; } pf;
    pf.u[0] = (g == 0) ? A0 : (g == 1) ? pc0 : (g == 2) ? c0  : sp0;
    pf.u[1] = (g == 0) ? A1 : (g == 1) ? pc1 : (g == 2) ? c1  : sp1;
    pf.u[2] = (g == 0) ? sp0 : (g == 1) ? c0 : (g == 2) ? pc0 : B0;
    pf.u[3] = (g == 0) ? sp1 : (g == 1) ? c1 : (g == 2) ? pc1 : B1;
    // ---- PV ----
    __builtin_amdgcn_s_setprio(1);
    #pragma unroll
    for (int hf = 0; hf < 16; hf++){
      const char* vr = Vb + (size_t)(hf*16 + lr)*64;
      short8 v0 = *(const short8*)(vr + (lkq16 ^ swv));
      o_[hf] = mfma16(v0, pf.v, o_[hf]);
    }
    __builtin_amdgcn_s_setprio(0);
  }
  // ---- epilogue ----
  lrow += __shfl_xor(lrow, 16, 64);
  lrow += __shfl_xor(lrow, 32, 64);
  u16* eb = enc + ((size_t)(b*1024 + q0 + lr)) * 2048 + head*256;
  float inv = 1.0f / lrow;
  #pragma unroll
  for (int hf = 0; hf < 16; hf++){
    u16x4 st = { f2bf(o_[hf][0] * inv), f2bf(o_[hf][1] * inv),
                 f2bf(o_[hf][2] * inv), f2bf(o_[hf][3] * inv) };
    *reinterpret_cast<u16x4*>(eb + hf*16 + g*4) = st;
  }
}

extern "C" void kernel_launch(void* const* d_in, const int* in_sizes, int n_in,
                              void* d_out, int out_size, void* d_ws, size_t ws_size,
                              hipStream_t stream){
  const float* x0     = (const float*)d_in[0];
  const float* x1     = (const float*)d_in[1];
  const int*   pos    = (const int*)d_in[2];
  const float* q0_w   = (const float*)d_in[4];
  const float* kv0_w  = (const float*)d_in[5];
  const float* out0_w = (const float*)d_in[6];
  const float* q1_w   = (const float*)d_in[7];
  const float* kv1_w  = (const float*)d_in[8];
  const float* out1_w = (const float*)d_in[9];

  float* out  = (float*)d_out;
  float* out0 = out;
  float* out1 = out + 6291456;
  float* idxp = out + 7340032;
  float* kout = out + 7340036;
  float* vout = out + 8388612;

  char* ws = (char*)d_ws;
  size_t off = 0;
  auto alloc = [&](size_t bytes){
    void* p = ws + off;
    off = (off + bytes + 255) & ~(size_t)255;
    return p;
  };
  u16* x0b   = (u16*)alloc((size_t)6291456 * 2);
  u16* x1b   = (u16*)alloc((size_t)1048576 * 2);
  u16* qkv0T = (u16*)alloc((size_t)2560 * 2048 * 2);
  u16* qkv1T = (u16*)alloc((size_t)2560 * 1024 * 2);
  u16* o0T   = (u16*)alloc((size_t)2048 * 2048 * 2);
  u16* o1T   = (u16*)alloc((size_t)1024 * 2048 * 2);
  u16* qkvb  = (u16*)alloc((size_t)4096 * 2560 * 2);
  u16* vTb   = (u16*)alloc((size_t)4 * 256 * 1024 * 2);
  u16* encb  = (u16*)alloc((size_t)4096 * 2048 * 2);

  hipFuncSetAttribute((const void*)attn_kernel,
                      hipFuncAttributeMaxDynamicSharedMemorySize, 65536);
  hipFuncSetAttribute((const void*)gemm_qkv,
                      hipFuncAttributeMaxDynamicSharedMemorySize, 65536);
  hipFuncSetAttribute((const void*)gemm_out,
                      hipFuncAttributeMaxDynamicSharedMemorySize, 65536);

  prep_all<<<20992, 256, 0, stream>>>(x0, x1, x0b, x1b,
                                      q0_w, kv0_w, q1_w, kv1_w, out0_w, out1_w,
                                      qkv0T, qkv1T, o0T, o1T);

  gemm_qkv<<<640, 256, 65536, stream>>>(x0b, qkv0T, x1b, qkv1T, qkvb);

  rope_tv<<<3072, 256, 0, stream>>>(qkvb, pos, kout, vout, idxp, vTb);

  attn_kernel<<<512, 256, 65536, stream>>>(qkvb, vTb, encb);

  gemm_out<<<448, 256, 65536, stream>>>(encb, o0T, o1T, out0, out1);
}